// Round 1
// baseline (46.758 us; speedup 1.0000x reference)
//
#include <hip/hip_runtime.h>

// 4x4 spiking array multiplier == exact 4-bit x 4-bit binary multiply.
// Inputs A, B: (N,4) float32 with values in {0,1}. Output: (N,8) float32,
// the bits of the 8-bit product, LSB first.
//
// Purely memory-bound: 256 MiB total traffic at N=4M -> ~43 us floor @6.3 TB/s.

__global__ __launch_bounds__(256) void mult4x4_kernel(
    const float4* __restrict__ A4,   // N rows of 4 floats each == one float4
    const float4* __restrict__ B4,
    float4* __restrict__ O4,         // N rows of 8 floats == two float4
    int n)
{
    int i = blockIdx.x * blockDim.x + threadIdx.x;
    if (i >= n) return;

    float4 a = A4[i];
    float4 b = B4[i];

    // Inputs are exactly 0.0f or 1.0f; pack to 4-bit ints.
    int ai = (a.x != 0.0f ? 1 : 0)
           | (a.y != 0.0f ? 2 : 0)
           | (a.z != 0.0f ? 4 : 0)
           | (a.w != 0.0f ? 8 : 0);
    int bi = (b.x != 0.0f ? 1 : 0)
           | (b.y != 0.0f ? 2 : 0)
           | (b.z != 0.0f ? 4 : 0)
           | (b.w != 0.0f ? 8 : 0);

    int p = ai * bi;  // 8-bit product

    float4 lo, hi;
    lo.x = (float)( p       & 1);
    lo.y = (float)((p >> 1) & 1);
    lo.z = (float)((p >> 2) & 1);
    lo.w = (float)((p >> 3) & 1);
    hi.x = (float)((p >> 4) & 1);
    hi.y = (float)((p >> 5) & 1);
    hi.z = (float)((p >> 6) & 1);
    hi.w = (float)((p >> 7) & 1);

    O4[2 * i]     = lo;
    O4[2 * i + 1] = hi;
}

extern "C" void kernel_launch(void* const* d_in, const int* in_sizes, int n_in,
                              void* d_out, int out_size, void* d_ws, size_t ws_size,
                              hipStream_t stream)
{
    const float4* A4 = (const float4*)d_in[0];
    const float4* B4 = (const float4*)d_in[1];
    float4* O4 = (float4*)d_out;

    int n = in_sizes[0] / 4;  // number of rows
    int block = 256;
    int grid = (n + block - 1) / block;
    mult4x4_kernel<<<grid, block, 0, stream>>>(A4, B4, O4, n);
}